// Round 13
// baseline (342.048 us; speedup 1.0000x reference)
//
#include <hip/hip_runtime.h>

typedef _Float16 f16;
typedef f16 f16x2 __attribute__((ext_vector_type(2)));
typedef f16 f16x4 __attribute__((ext_vector_type(4)));
typedef f16 f16x8 __attribute__((ext_vector_type(8)));
typedef float f32x4 __attribute__((ext_vector_type(4)));

#define AS1 __attribute__((address_space(1)))
#define AS3 __attribute__((address_space(3)))

#define NN 8192
#define EE 32768

#if __has_builtin(__builtin_amdgcn_fdot2)
#define HAS_FDOT2 1
#else
#define HAS_FDOT2 0
#endif

__device__ __forceinline__ void glds16(const void* g, void* l) {
  __builtin_amdgcn_global_load_lds((const AS1 unsigned int*)g, (AS3 unsigned int*)l, 16, 0, 0);
}
// cooperative stage, 256 threads, 16B/lane; LDS base passed wave-uniform
__device__ __forceinline__ void stage_bytes(const void* g, void* s, int nbytes, int tid) {
  const int lane = tid & 63;
  for (int off = tid * 16; off < nbytes; off += 4096)
    glds16((const char*)g + off, (char*)s + (off - lane * 16));
}

// ---------------- prep: h0 GEMM, ehh, W2 fragment repack (80 kg), weight casts, segstarts, CSR ----
__global__ void prep_kernel(
    const float* __restrict__ nf, const float* __restrict__ ef,
    const float* __restrict__ W_in, const float* __restrict__ b_in,
    const float* __restrict__ W1, const float* __restrict__ b1,
    const float* __restrict__ W2, const float* __restrict__ b2,
    const float* __restrict__ gWih, const float* __restrict__ gWhh,
    const float* __restrict__ lWih, const float* __restrict__ lWhh,
    const int* __restrict__ batch, const int* __restrict__ Etgt,
    float* __restrict__ h, f16* __restrict__ hf, f16* __restrict__ ehh,
    f16* __restrict__ W2f, f16* __restrict__ WihT, f16* __restrict__ WhhT,
    f16* __restrict__ Wcat, int* __restrict__ segstarts,
    int* __restrict__ count, int* __restrict__ bucket) {
  int t = blockIdx.x * 256 + threadIdx.x;
  if (t < 786432) {                       // h0: [8192][96] fp32+f16, pads zero
    int n = t / 96, i = t - n * 96;
    float v = 0.f;
    if (i < 73) {
      v = b_in[i];
      const float* nr = nf + n * 32;
      #pragma unroll
      for (int f = 0; f < 32; ++f) v += nr[f] * W_in[f * 73 + i];
    }
    h[t] = v; hf[t] = (f16)v;
    return;
  }
  t -= 786432;
  if (t < 2621440) {                      // ehh: [32768][80], col73 = 1.0 (bias), cols 74-79 zero
    int e = t / 80, k = t - e * 80;
    float v;
    if (k < 73) {
      v = b1[k];
      const float* er = ef + e * 16;
      #pragma unroll
      for (int f = 0; f < 16; ++f) v += er[f] * W1[f * 73 + k];
      v = fmaxf(v, 0.f);
    } else v = (k == 73) ? 1.f : 0.f;
    ehh[t] = (f16)v;
    return;
  }
  t -= 2621440;
  if (t < 614400) {                       // W2f: [80 kg][5 nt][3 ks][64 lane][8]; kg>=74 zero
    int kg = t / 7680, r = t - kg * 7680;
    int nt = r / 1536, r2 = r - nt * 1536;
    int ks = r2 / 512, r3 = r2 - ks * 512;
    int l = r3 >> 3, j = r3 & 7;
    int mr = l & 15, q = l >> 4;
    int i = nt * 16 + mr, jj = ks * 32 + q * 8 + j;
    float v = 0.f;
    if (i < 73 && jj < 73) {
      if (kg < 73) v = W2[kg * 5329 + i * 73 + jj];
      else if (kg == 73) v = b2[i * 73 + jj];
    }
    W2f[t] = (f16)v;
    return;
  }
  t -= 614400;
  if (t < 43008) {                        // WihT/WhhT: [224][96]
    int half = t / 21504, r = t - half * 21504;
    int g = r / 96, k = r - g * 96;
    float v = 0.f;
    if (g < 219 && k < 73) v = half ? gWhh[g * 73 + k] : gWih[g * 73 + k];
    (half ? WhhT : WihT)[r] = (f16)v;
    return;
  }
  t -= 43008;
  if (t < 67744) {                        // Wcat[292][232]: [0..72]=wih_q [76..148]=wih_r [152..224]=whh
    int g = t / 232, k = t - g * 232;
    float v = 0.f;
    if (k < 73) v = lWih[g * 146 + k];
    else if (k >= 76 && k < 149) v = lWih[g * 146 + (k - 3)];
    else if (k >= 152 && k < 225) v = lWhh[g * 73 + (k - 152)];
    Wcat[t] = (f16)v;
    return;
  }
  t -= 67744;
  if (t < 65) {                           // segstarts: lower_bound(batch, t)
    int key = t, lo = 0, hi = NN;
    while (lo < hi) { int mid = (lo + hi) >> 1; if (batch[mid] < key) lo = mid + 1; else hi = mid; }
    segstarts[t] = lo;
    return;
  }
  t -= 65;
  if (t < EE) {                           // bucket fill: CSR-by-target (cap 64, λ=4)
    int tg = Etgt[t];
    int slot = atomicAdd(&count[tg], 1);
    if (slot < 64) bucket[tg * 64 + slot] = t;
  }
}

// ---------------- edge-network matvec: m[e,i] = sum_{kg,j} ehh[e,kg] * hf[src[e],j] * W2[kg][i][j] ----
// 512 blocks x 256 threads: bm (128) x ksp (4). Block owns 256 edges (4 m-tiles/wave, 4 waves)
// over K-quarter kg[ksp*20,(ksp+1)*20). Quarters write DISJOINT fp32 ranges m[e][ksp*80+i]
// (single writer, no atomics). Chunk = 2 kg -> LDS 61.4KB -> 2 blocks/CU (2 waves/SIMD).
__global__ __launch_bounds__(256, 2) void vgemm_kernel(
    const f16* __restrict__ ehh, const f16* __restrict__ hf,
    const f16* __restrict__ W2f, const int* __restrict__ Esrc,
    float* __restrict__ m) {
  __shared__ __align__(16) f16 w2s[2][15360];     // 2 x 30720 B (2-kg chunks, fragment order)
  const int tid = threadIdx.x;
  const int bm = blockIdx.x & 127, ksp = blockIdx.x >> 7;
  const int e0 = bm * 256;
  const int kg0 = ksp * 20;
  const int wave = tid >> 6, lane = tid & 63;
  const int q = lane >> 4, mr = lane & 15;

  stage_bytes(W2f + kg0 * 7680, w2s[0], 30720, tid);

  // hf fragments in registers: wave owns 4 m-tiles (rows e0+wave*64+mt*16+mr)
  f16x8 hsv[4][3];
  size_t er80[4];
  #pragma unroll
  for (int mt = 0; mt < 4; ++mt) {
    int er = e0 + wave * 64 + mt * 16 + mr;
    int srcn = Esrc[er];
    er80[mt] = (size_t)er * 80;
    #pragma unroll
    for (int ks = 0; ks < 3; ++ks)
      hsv[mt][ks] = *(const f16x8*)(hf + (size_t)srcn * 96 + ks * 32 + q * 8);
  }

  f32x4 zero = {0.f, 0.f, 0.f, 0.f};
  f32x4 acc[4][5];
  #pragma unroll
  for (int mt = 0; mt < 4; ++mt)
    #pragma unroll
    for (int nt = 0; nt < 5; ++nt) acc[mt][nt] = zero;

  for (int ch = 0; ch < 10; ++ch) {
    // ev values for this chunk (2 kg): global->reg (L2-hot), issued before the barrier
    f16x2 evq[4];
    #pragma unroll
    for (int mt = 0; mt < 4; ++mt)
      evq[mt] = *(const f16x2*)(ehh + er80[mt] + kg0 + ch * 2);
    __syncthreads();                       // w2s[ch&1] staged
    if (ch + 1 < 10)
      stage_bytes(W2f + (kg0 + (ch + 1) * 2) * 7680, w2s[(ch + 1) & 1], 30720, tid);
    const f16* wb = w2s[ch & 1];
    #pragma unroll
    for (int i = 0; i < 2; ++i) {
      f16x8 af[4][3];
      #pragma unroll
      for (int mt = 0; mt < 4; ++mt) {
        f16 ev = evq[mt][i];
        f16x8 evv = {ev, ev, ev, ev, ev, ev, ev, ev};
        #pragma unroll
        for (int ks = 0; ks < 3; ++ks) af[mt][ks] = hsv[mt][ks] * evv;
      }
      const f16* wbi = wb + i * 7680;
      #pragma unroll
      for (int nt = 0; nt < 5; ++nt) {
        #pragma unroll
        for (int ks = 0; ks < 3; ++ks) {
          f16x8 bf = *(const f16x8*)(wbi + (nt * 3 + ks) * 512 + lane * 8);  // base+lane*16: conflict-free
          #pragma unroll
          for (int mt = 0; mt < 4; ++mt)
            acc[mt][nt] = __builtin_amdgcn_mfma_f32_16x16x32_f16(af[mt][ks], bf, acc[mt][nt], 0, 0, 0);
        }
      }
    }
  }
  // epilogue: C layout col=lane&15, row=(lane>>4)*4+reg; fp32 stores to disjoint quarter-row
  #pragma unroll
  for (int mt = 0; mt < 4; ++mt) {
    #pragma unroll
    for (int reg = 0; reg < 4; ++reg) {
      int er = e0 + wave * 64 + mt * 16 + q * 4 + reg;
      float* mp = m + (size_t)er * 320 + ksp * 80;
      #pragma unroll
      for (int nt = 0; nt < 5; ++nt)
        mp[nt * 16 + mr] = acc[mt][nt][reg];
    }
  }
}

// ---------------- gather: agg[n,i] = sum over incoming edges of all 4 K-quarters, emits f16 ----
__global__ void gather_kernel(const float* __restrict__ m, const int* __restrict__ count,
                              const int* __restrict__ bucket, f16* __restrict__ aggf) {
  int t = blockIdx.x * 384 + threadIdx.x;  // exactly 8192*96
  int n = t / 96, i = t - n * 96;
  float s = 0.f;
  if (i < 80) {
    int cnt = count[n]; if (cnt > 64) cnt = 64;
    const int* bk = bucket + n * 64;
    for (int j = 0; j < cnt; ++j) {
      const float* mp = m + (size_t)bk[j] * 320;
      s += (mp[i] + mp[80 + i]) + (mp[160 + i] + mp[240 + i]);
    }
  }
  aggf[t] = (f16)s;
}

// ---------------- GRU gates GEMMs: G[0]=agg@WihT, G[1]=h@WhhT ----------------
__global__ __launch_bounds__(256, 1) void grugemm_kernel(
    const f16* __restrict__ aggf, const f16* __restrict__ hf,
    const f16* __restrict__ WihT, const f16* __restrict__ WhhT,
    float* __restrict__ G) {
  __shared__ __align__(16) f16 As[128 * 96];
  __shared__ __align__(16) f16 Bs[224 * 96];
  const int tid = threadIdx.x;
  const int bz = blockIdx.x >> 6, bm = blockIdx.x & 63;
  const int m0 = bm * 128;
  const f16* A = bz ? hf : aggf;
  const f16* B = bz ? WhhT : WihT;
  float* out = G + bz * (NN * 224);
  stage_bytes(A + m0 * 96, As, 128 * 96 * 2, tid);
  stage_bytes(B, Bs, 224 * 96 * 2, tid);
  const int wave = tid >> 6, lane = tid & 63, q = lane >> 4, mr = lane & 15;
  __syncthreads();
  f16x8 af[2][3];
  #pragma unroll
  for (int mt = 0; mt < 2; ++mt)
    #pragma unroll
    for (int ks = 0; ks < 3; ++ks)
      af[mt][ks] = *(const f16x8*)(As + (wave * 32 + mt * 16 + mr) * 96 + ks * 32 + q * 8);
  f32x4 zero = {0.f, 0.f, 0.f, 0.f};
  f32x4 acc[2][14];
  #pragma unroll
  for (int mt = 0; mt < 2; ++mt)
    #pragma unroll
    for (int nt = 0; nt < 14; ++nt) acc[mt][nt] = zero;
  #pragma unroll
  for (int nt = 0; nt < 14; ++nt) {
    #pragma unroll
    for (int ks = 0; ks < 3; ++ks) {
      f16x8 bf = *(const f16x8*)(Bs + (nt * 16 + mr) * 96 + ks * 32 + q * 8);
      #pragma unroll
      for (int mt = 0; mt < 2; ++mt)
        acc[mt][nt] = __builtin_amdgcn_mfma_f32_16x16x32_f16(af[mt][ks], bf, acc[mt][nt], 0, 0, 0);
    }
  }
  #pragma unroll
  for (int mt = 0; mt < 2; ++mt)
    #pragma unroll
    for (int reg = 0; reg < 4; ++reg) {
      int row = m0 + wave * 32 + mt * 16 + q * 4 + reg;
      #pragma unroll
      for (int nt = 0; nt < 14; ++nt)
        out[row * 224 + nt * 16 + mr] = acc[mt][nt][reg];
    }
}

// ---------------- GRU elementwise update ----------------
__global__ void gate_kernel(const float* __restrict__ G, const float* __restrict__ bih,
                            const float* __restrict__ bhh, float* __restrict__ h,
                            f16* __restrict__ hf) {
  int idx = blockIdx.x * 256 + threadIdx.x;  // exactly 8192*73
  int n = idx / 73, i = idx - n * 73;
  const float* g0 = G + n * 224;
  const float* g1 = G + NN * 224 + n * 224;
  float rr = g0[i] + bih[i] + g1[i] + bhh[i];
  rr = 1.f / (1.f + __expf(-rr));
  float zz = g0[73 + i] + bih[73 + i] + g1[73 + i] + bhh[73 + i];
  zz = 1.f / (1.f + __expf(-zz));
  float nx = g0[146 + i] + bih[146 + i] + rr * (g1[146 + i] + bhh[146 + i]);
  float nn_ = 2.f / (1.f + __expf(-2.f * nx)) - 1.f;
  float hv = h[n * 96 + i];
  float hn = (1.f - zz) * nn_ + zz * hv;
  h[n * 96 + i] = hn;
  hf[n * 96 + i] = (f16)hn;
}

// ---------------- Set2Set helpers ----------------
__device__ __forceinline__ float wred_sum(float v) {
  #pragma unroll
  for (int off = 32; off; off >>= 1) v += __shfl_xor(v, off, 64);
  return v;
}
// fp32-accumulating f16 dots (v_dot2_f32_f16)
__device__ __forceinline__ float dot8(f16x8 w, f16x8 x, float acc) {
#if HAS_FDOT2
  acc = __builtin_amdgcn_fdot2((f16x2)__builtin_shufflevector(w, w, 0, 1),
                               (f16x2)__builtin_shufflevector(x, x, 0, 1), acc, false);
  acc = __builtin_amdgcn_fdot2((f16x2)__builtin_shufflevector(w, w, 2, 3),
                               (f16x2)__builtin_shufflevector(x, x, 2, 3), acc, false);
  acc = __builtin_amdgcn_fdot2((f16x2)__builtin_shufflevector(w, w, 4, 5),
                               (f16x2)__builtin_shufflevector(x, x, 4, 5), acc, false);
  acc = __builtin_amdgcn_fdot2((f16x2)__builtin_shufflevector(w, w, 6, 7),
                               (f16x2)__builtin_shufflevector(x, x, 6, 7), acc, false);
#else
  #pragma unroll
  for (int e = 0; e < 8; ++e) acc += (float)w[e] * (float)x[e];
#endif
  return acc;
}
__device__ __forceinline__ float dot4(f16x4 w, f16x4 x, float acc) {
#if HAS_FDOT2
  acc = __builtin_amdgcn_fdot2((f16x2)__builtin_shufflevector(w, w, 0, 1),
                               (f16x2)__builtin_shufflevector(x, x, 0, 1), acc, false);
  acc = __builtin_amdgcn_fdot2((f16x2)__builtin_shufflevector(w, w, 2, 3),
                               (f16x2)__builtin_shufflevector(x, x, 2, 3), acc, false);
#else
  #pragma unroll
  for (int e = 0; e < 4; ++e) acc += (float)w[e] * (float)x[e];
#endif
  return acc;
}

#define S2SCAP 256   // absolute per-segment cap (binomial mean 128, sd 11)
#define NCAP 190     // rows cached in LDS; [NCAP,segT) via global fallback (normally empty)

// ---------------- Set2Set v7: (512,2) -> 256-VGPR budget so LSTM weights STAY resident ----
// r12 evidence: without the min-waves arg the compiler targeted high occupancy (VGPR=96)
// and rematerialized the 116-VGPR weight array from L2 every iteration (FETCH 1.37MB).
// Only 64 blocks launch (1/CU on a quarter of the chip) -> occupancy is worthless here;
// trade it for registers.
__global__ __launch_bounds__(512, 2) void s2s_kernel(
    const float* __restrict__ h, const f16* __restrict__ hf,
    const f16* __restrict__ Wcat,
    const float* __restrict__ lbih, const float* __restrict__ lbhh,
    const float* __restrict__ Wout, const float* __restrict__ bout,
    const int* __restrict__ segstarts, float* __restrict__ out) {
  __shared__ __align__(16) f16 hseg[NCAP * 84];   // 31920 B, row stride 84 f16 (b64-aligned)
  __shared__ __align__(16) f16 xcat[240];
  __shared__ float hhv[80];
  __shared__ float gatesv[292];
  __shared__ float earr[S2SCAP];
  __shared__ float red[4];
  __shared__ __align__(16) float rpart[19 * 80];
  const int t = threadIdx.x, b = blockIdx.x;
  const int wid = t >> 6, lane = t & 63;

  const int s0 = segstarts[b];
  int segT = segstarts[b + 1] - s0;
  if (segT > S2SCAP) segT = S2SCAP;
  const int c = segT < NCAP ? segT : NCAP;

  if (t < 240) xcat[t] = (f16)0.f;
  if (t < 80) hhv[t] = 0.f;

  // stage hseg rows (f16, cols 0..75 data incl. zero pads 73..75; cols 76..83 zeroed)
  for (int r = wid; r < c; r += 8) {
    if (lane < 19) {
      f16x4 v = *(const f16x4*)(hf + (size_t)(s0 + r) * 96 + lane * 4);
      *(f16x4*)(hseg + r * 84 + lane * 4) = v;
    } else if (lane < 21) {
      f16x4 z = {(f16)0.f, (f16)0.f, (f16)0.f, (f16)0.f};
      *(f16x4*)(hseg + r * 84 + 76 + (lane - 19) * 4) = z;
    }
  }

  const bool isg = (t >= 220);
  const int g2 = t - 220;
  float bias = 0.f;
  if (isg) bias = lbih[g2] + lbhh[g2];
  // LSTM weight row RESIDENT in registers (116 VGPR), loaded unconditionally (clamped row).
  f16x8 wihF[19], whhF[10];
  {
    const f16* wr = Wcat + (size_t)(isg ? g2 : 0) * 232;
    #pragma unroll
    for (int v = 0; v < 19; ++v) wihF[v] = *(const f16x8*)(wr + v * 8);
    #pragma unroll
    for (int v = 0; v < 10; ++v) whhF[v] = *(const f16x8*)(wr + 152 + v * 8);
  }
  const int nc = t / 10, fo = t - nc * 10;    // readout mapping (t<190)
  float creg = 0.f;                            // LSTM cell state (t<73)
  __syncthreads();

  for (int iter = 0; iter < 12; ++iter) {
    // ---- P1: LSTM gate matvec (292 threads), weights in regs, 4 accumulators ----
    if (isg) {
      float a0 = bias, a1 = 0.f, a2 = 0.f, a3 = 0.f;
      #pragma unroll
      for (int v = 0; v < 19; ++v) {
        f16x8 x = *(const f16x8*)(xcat + v * 8);
        int sel = v & 3;
        if (sel == 0) a0 = dot8(wihF[v], x, a0);
        else if (sel == 1) a1 = dot8(wihF[v], x, a1);
        else if (sel == 2) a2 = dot8(wihF[v], x, a2);
        else a3 = dot8(wihF[v], x, a3);
      }
      #pragma unroll
      for (int v = 0; v < 10; ++v) {
        f16x8 x = *(const f16x8*)(xcat + 152 + v * 8);
        int sel = v & 3;
        if (sel == 0) a0 = dot8(whhF[v], x, a0);
        else if (sel == 1) a1 = dot8(whhF[v], x, a1);
        else if (sel == 2) a2 = dot8(whhF[v], x, a2);
        else a3 = dot8(whhF[v], x, a3);
      }
      gatesv[g2] = (a0 + a1) + (a2 + a3);
    }
    __syncthreads();
    // ---- P2: LSTM elementwise update (t<73) ----
    if (t < 73) {
      float ig = 1.f / (1.f + __expf(-gatesv[t]));
      float fg = 1.f / (1.f + __expf(-gatesv[73 + t]));
      float gx = gatesv[146 + t];
      float gg = 2.f / (1.f + __expf(-2.f * gx)) - 1.f;
      float og = 1.f / (1.f + __expf(-gatesv[219 + t]));
      creg = fg * creg + ig * gg;
      float cth = 2.f / (1.f + __expf(-2.f * creg)) - 1.f;
      float hh = og * cth;
      hhv[t] = hh;
      xcat[t] = (f16)hh;        // q slot
      xcat[152 + t] = (f16)hh;  // hh slot
    }
    __syncthreads();
    // ---- P3: logits + exp + per-wave sums (t<192, node per thread, f16 dot) ----
    if (wid < 3) {
      float a = 0.f;
      if (t < c) {
        const f16* hp = hseg + t * 84;
        float e0 = 0.f, e1 = 0.f;
        #pragma unroll
        for (int k = 0; k < 9; ++k) {
          f16x4 h0 = *(const f16x4*)(hp + 8 * k);
          f16x4 h1 = *(const f16x4*)(hp + 8 * k + 4);
          f16x4 x0 = *(const f16x4*)(xcat + 8 * k);
          f16x4 x1 = *(const f16x4*)(xcat + 8 * k + 4);
          e0 = dot4(h0, x0, e0);
          e1 = dot4(h1, x1, e1);
        }
        f16x4 ht = *(const f16x4*)(hp + 72);
        f16x4 xt = *(const f16x4*)(xcat + 72);
        e0 = dot4(ht, xt, e0);
        a = __expf(fminf(e0 + e1, 80.f));  // logits bounded; no max-sub in fp32
        earr[t] = a;
      }
      float ws = wred_sum(a);
      if (lane == 0) red[wid] = ws;
    }
    // fallback logits for nodes >= NCAP (normally zero-trip)
    if (wid == 0) {
      float fa = 0.f;
      int n = NCAP + lane;
      if (n < segT) {
        const float* hr = h + (size_t)(s0 + n) * 96;
        float e = 0.f;
        for (int i = 0; i < 73; ++i) e += hr[i] * hhv[i];
        fa = __expf(fminf(e, 80.f));
        earr[n] = fa;
      }
      float ws2 = wred_sum(fa);
      if (lane == 0) red[3] = ws2;
    }
    __syncthreads();
    // ---- P4: weighted readout partials (t<190: chunk nc of 10 nodes, feature-octet fo) ----
    if (t < 190) {
      float r0 = 0.f, r1 = 0.f, r2 = 0.f, r3 = 0.f, r4 = 0.f, r5 = 0.f, r6 = 0.f, r7 = 0.f;
      #pragma unroll
      for (int j = 0; j < 10; ++j) {
        int n = nc * 10 + j;
        if (n < c) {
          float a = earr[n];
          const f16* hp = hseg + n * 84 + fo * 8;
          f16x4 v0 = *(const f16x4*)(hp);
          f16x4 v1 = *(const f16x4*)(hp + 4);
          r0 += a * (float)v0[0]; r1 += a * (float)v0[1];
          r2 += a * (float)v0[2]; r3 += a * (float)v0[3];
          r4 += a * (float)v1[0]; r5 += a * (float)v1[1];
          r6 += a * (float)v1[2]; r7 += a * (float)v1[3];
        }
      }
      if (nc == 18) {  // fallback nodes from global hf (normally zero-trip)
        for (int n = NCAP; n < segT; ++n) {
          float a = earr[n];
          const f16* hp = hf + (size_t)(s0 + n) * 96 + fo * 8;
          f16x4 v0 = *(const f16x4*)(hp);
          f16x4 v1 = *(const f16x4*)(hp + 4);
          r0 += a * (float)v0[0]; r1 += a * (float)v0[1];
          r2 += a * (float)v0[2]; r3 += a * (float)v0[3];
          r4 += a * (float)v1[0]; r5 += a * (float)v1[1];
          r6 += a * (float)v1[2]; r7 += a * (float)v1[3];
        }
      }
      f32x4 wa = {r0, r1, r2, r3}, wb = {r4, r5, r6, r7};
      *(f32x4*)(rpart + nc * 80 + fo * 8) = wa;
      *(f32x4*)(rpart + nc * 80 + fo * 8 + 4) = wb;
    }
    __syncthreads();
    // ---- P5: combine partials -> r into xcat (t<80) ----
    if (t < 80) {
      float S = red[0] + red[1] + red[2] + red[3];
      float invS = (S > 0.f) ? (1.f / S) : 0.f;
      float r = 0.f;
      #pragma unroll
      for (int ch = 0; ch < 19; ++ch) r += rpart[ch * 80 + t];
      if (t < 73) xcat[76 + t] = (f16)(r * invS);
    }
    __syncthreads();
  }
  // ---- output: out[b] = bout + hh . Wout ----
  if (t < 80) gatesv[t] = (t < 73) ? hhv[t] * Wout[t] : 0.f;
  __syncthreads();
  if (t == 0) {
    float a = bout[0];
    for (int i = 0; i < 73; ++i) a += gatesv[i];
    out[b] = a;
  }
}

// ---------------- workspace layout (bytes; ws_size = 256 MiB per harness fill) ----------------
#define OFF_H      0u          // float [8192][96]
#define OFF_G      3145728u    // float [2][8192][224]
#define OFF_HF     17825792u   // f16 [8192][96]
#define OFF_AGGF   19398656u   // f16 [8192][96]
#define OFF_EHH    20971520u   // f16 [32768][80]
#define OFF_W2F    26214400u   // f16 [80][7680] fragment order
#define OFF_WIHT   27443200u   // f16 [224][96]
#define OFF_WHHT   27486208u   // f16 [224][96]
#define OFF_WCAT   27529216u   // f16 [292][232]
#define OFF_SEG    27664704u   // int [65]
#define OFF_CNT    27665024u   // int [8192]
#define OFF_BKT    27697792u   // int [8192][64]
#define OFF_M      29794944u   // float [32768][320] K-quarter partials (end ~71.7 MB)

extern "C" void kernel_launch(void* const* d_in, const int* in_sizes, int n_in,
                              void* d_out, int out_size, void* d_ws, size_t ws_size,
                              hipStream_t stream) {
  const float* nf   = (const float*)d_in[0];
  const float* ef   = (const float*)d_in[1];
  const float* W_in = (const float*)d_in[2];
  const float* b_in = (const float*)d_in[3];
  const float* W1   = (const float*)d_in[4];
  const float* b1   = (const float*)d_in[5];
  const float* W2   = (const float*)d_in[6];
  const float* b2   = (const float*)d_in[7];
  const float* gWih = (const float*)d_in[8];
  const float* gWhh = (const float*)d_in[9];
  const float* gbih = (const float*)d_in[10];
  const float* gbhh = (const float*)d_in[11];
  const float* lWih = (const float*)d_in[12];
  const float* lWhh = (const float*)d_in[13];
  const float* lbih = (const float*)d_in[14];
  const float* lbhh = (const float*)d_in[15];
  const float* Wout = (const float*)d_in[16];
  const float* bout = (const float*)d_in[17];
  const int* Esrc   = (const int*)d_in[18];
  const int* Etgt   = (const int*)d_in[19];
  const int* batch  = (const int*)d_in[20];

  char* ws = (char*)d_ws;
  float* h    = (float*)(ws + OFF_H);
  float* G    = (float*)(ws + OFF_G);
  float* m    = (float*)(ws + OFF_M);
  f16* hf     = (f16*)(ws + OFF_HF);
  f16* aggf   = (f16*)(ws + OFF_AGGF);
  f16* ehh    = (f16*)(ws + OFF_EHH);
  f16* W2f    = (f16*)(ws + OFF_W2F);
  f16* WihT   = (f16*)(ws + OFF_WIHT);
  f16* WhhT   = (f16*)(ws + OFF_WHHT);
  f16* Wcat   = (f16*)(ws + OFF_WCAT);
  int* segst  = (int*)(ws + OFF_SEG);
  int* cnt    = (int*)(ws + OFF_CNT);
  int* bkt    = (int*)(ws + OFF_BKT);

  hipMemsetAsync(cnt, 0, NN * sizeof(int), stream);
  prep_kernel<<<16273, 256, 0, stream>>>(nf, ef, W_in, b_in, W1, b1, W2, b2,
                                         gWih, gWhh, lWih, lWhh, batch, Etgt,
                                         h, hf, ehh, W2f, WihT, WhhT, Wcat,
                                         segst, cnt, bkt);
  for (int step = 0; step < 3; ++step) {
    vgemm_kernel<<<512, 256, 0, stream>>>(ehh, hf, W2f, Esrc, m);
    gather_kernel<<<2048, 384, 0, stream>>>(m, cnt, bkt, aggf);
    grugemm_kernel<<<128, 256, 0, stream>>>(aggf, hf, WihT, WhhT, G);
    gate_kernel<<<2336, 256, 0, stream>>>(G, gbih, gbhh, h, hf);
  }
  s2s_kernel<<<64, 512, 0, stream>>>(h, hf, Wcat, lbih, lbhh, Wout, bout, segst,
                                     (float*)d_out);
}

// Round 14
// 330.901 us; speedup vs baseline: 1.0337x; 1.0337x over previous
//
#include <hip/hip_runtime.h>

typedef _Float16 f16;
typedef f16 f16x2 __attribute__((ext_vector_type(2)));
typedef f16 f16x4 __attribute__((ext_vector_type(4)));
typedef f16 f16x8 __attribute__((ext_vector_type(8)));
typedef float f32x4 __attribute__((ext_vector_type(4)));

#define AS1 __attribute__((address_space(1)))
#define AS3 __attribute__((address_space(3)))

#define NN 8192
#define EE 32768

#if __has_builtin(__builtin_amdgcn_fdot2)
#define HAS_FDOT2 1
#else
#define HAS_FDOT2 0
#endif

__device__ __forceinline__ void glds16(const void* g, void* l) {
  __builtin_amdgcn_global_load_lds((const AS1 unsigned int*)g, (AS3 unsigned int*)l, 16, 0, 0);
}
// cooperative stage, 256 threads, 16B/lane; LDS base passed wave-uniform
__device__ __forceinline__ void stage_bytes(const void* g, void* s, int nbytes, int tid) {
  const int lane = tid & 63;
  for (int off = tid * 16; off < nbytes; off += 4096)
    glds16((const char*)g + off, (char*)s + (off - lane * 16));
}

// ---------------- prep: h0 GEMM, ehh, W2 fragment repack (80 kg), weight casts, segstarts, CSR ----
__global__ void prep_kernel(
    const float* __restrict__ nf, const float* __restrict__ ef,
    const float* __restrict__ W_in, const float* __restrict__ b_in,
    const float* __restrict__ W1, const float* __restrict__ b1,
    const float* __restrict__ W2, const float* __restrict__ b2,
    const float* __restrict__ gWih, const float* __restrict__ gWhh,
    const float* __restrict__ lWih, const float* __restrict__ lWhh,
    const int* __restrict__ batch, const int* __restrict__ Etgt,
    float* __restrict__ h, f16* __restrict__ hf, f16* __restrict__ ehh,
    f16* __restrict__ W2f, f16* __restrict__ WihT, f16* __restrict__ WhhT,
    f16* __restrict__ Wcat, int* __restrict__ segstarts,
    int* __restrict__ count, int* __restrict__ bucket) {
  int t = blockIdx.x * 256 + threadIdx.x;
  if (t < 786432) {                       // h0: [8192][96] fp32+f16, pads zero
    int n = t / 96, i = t - n * 96;
    float v = 0.f;
    if (i < 73) {
      v = b_in[i];
      const float* nr = nf + n * 32;
      #pragma unroll
      for (int f = 0; f < 32; ++f) v += nr[f] * W_in[f * 73 + i];
    }
    h[t] = v; hf[t] = (f16)v;
    return;
  }
  t -= 786432;
  if (t < 2621440) {                      // ehh: [32768][80], col73 = 1.0 (bias), cols 74-79 zero
    int e = t / 80, k = t - e * 80;
    float v;
    if (k < 73) {
      v = b1[k];
      const float* er = ef + e * 16;
      #pragma unroll
      for (int f = 0; f < 16; ++f) v += er[f] * W1[f * 73 + k];
      v = fmaxf(v, 0.f);
    } else v = (k == 73) ? 1.f : 0.f;
    ehh[t] = (f16)v;
    return;
  }
  t -= 2621440;
  if (t < 614400) {                       // W2f: [80 kg][5 nt][3 ks][64 lane][8]; kg>=74 zero
    int kg = t / 7680, r = t - kg * 7680;
    int nt = r / 1536, r2 = r - nt * 1536;
    int ks = r2 / 512, r3 = r2 - ks * 512;
    int l = r3 >> 3, j = r3 & 7;
    int mr = l & 15, q = l >> 4;
    int i = nt * 16 + mr, jj = ks * 32 + q * 8 + j;
    float v = 0.f;
    if (i < 73 && jj < 73) {
      if (kg < 73) v = W2[kg * 5329 + i * 73 + jj];
      else if (kg == 73) v = b2[i * 73 + jj];
    }
    W2f[t] = (f16)v;
    return;
  }
  t -= 614400;
  if (t < 43008) {                        // WihT/WhhT: [224][96]
    int half = t / 21504, r = t - half * 21504;
    int g = r / 96, k = r - g * 96;
    float v = 0.f;
    if (g < 219 && k < 73) v = half ? gWhh[g * 73 + k] : gWih[g * 73 + k];
    (half ? WhhT : WihT)[r] = (f16)v;
    return;
  }
  t -= 43008;
  if (t < 67744) {                        // Wcat[292][232]: [0..72]=wih_q [76..148]=wih_r [152..224]=whh
    int g = t / 232, k = t - g * 232;
    float v = 0.f;
    if (k < 73) v = lWih[g * 146 + k];
    else if (k >= 76 && k < 149) v = lWih[g * 146 + (k - 3)];
    else if (k >= 152 && k < 225) v = lWhh[g * 73 + (k - 152)];
    Wcat[t] = (f16)v;
    return;
  }
  t -= 67744;
  if (t < 65) {                           // segstarts: lower_bound(batch, t)
    int key = t, lo = 0, hi = NN;
    while (lo < hi) { int mid = (lo + hi) >> 1; if (batch[mid] < key) lo = mid + 1; else hi = mid; }
    segstarts[t] = lo;
    return;
  }
  t -= 65;
  if (t < EE) {                           // bucket fill: CSR-by-target (cap 64, λ=4)
    int tg = Etgt[t];
    int slot = atomicAdd(&count[tg], 1);
    if (slot < 64) bucket[tg * 64 + slot] = t;
  }
}

// ---------------- edge-network matvec: m[e,i] = sum_{kg,j} ehh[e,kg] * hf[src[e],j] * W2[kg][i][j] ----
// 512 blocks x 256 threads: bm (128) x ksp (4). Block owns 256 edges (4 m-tiles/wave, 4 waves)
// over K-quarter kg[ksp*20,(ksp+1)*20). Quarters write DISJOINT f16 ranges m[e][ksp*80+i]
// (single writer, no atomics). Chunk = 2 kg -> LDS 61.4KB -> 2 blocks/CU (2 waves/SIMD).
// m stored f16 (r10 evidence: identical absmax vs fp32; halves the 42MB/step write).
__global__ __launch_bounds__(256, 2) void vgemm_kernel(
    const f16* __restrict__ ehh, const f16* __restrict__ hf,
    const f16* __restrict__ W2f, const int* __restrict__ Esrc,
    f16* __restrict__ m) {
  __shared__ __align__(16) f16 w2s[2][15360];     // 2 x 30720 B (2-kg chunks, fragment order)
  const int tid = threadIdx.x;
  const int bm = blockIdx.x & 127, ksp = blockIdx.x >> 7;
  const int e0 = bm * 256;
  const int kg0 = ksp * 20;
  const int wave = tid >> 6, lane = tid & 63;
  const int q = lane >> 4, mr = lane & 15;

  stage_bytes(W2f + kg0 * 7680, w2s[0], 30720, tid);

  // hf fragments in registers: wave owns 4 m-tiles (rows e0+wave*64+mt*16+mr)
  f16x8 hsv[4][3];
  size_t er80[4];
  #pragma unroll
  for (int mt = 0; mt < 4; ++mt) {
    int er = e0 + wave * 64 + mt * 16 + mr;
    int srcn = Esrc[er];
    er80[mt] = (size_t)er * 80;
    #pragma unroll
    for (int ks = 0; ks < 3; ++ks)
      hsv[mt][ks] = *(const f16x8*)(hf + (size_t)srcn * 96 + ks * 32 + q * 8);
  }

  f32x4 zero = {0.f, 0.f, 0.f, 0.f};
  f32x4 acc[4][5];
  #pragma unroll
  for (int mt = 0; mt < 4; ++mt)
    #pragma unroll
    for (int nt = 0; nt < 5; ++nt) acc[mt][nt] = zero;

  for (int ch = 0; ch < 10; ++ch) {
    // ev values for this chunk (2 kg): global->reg (L2-hot), issued before the barrier
    f16x2 evq[4];
    #pragma unroll
    for (int mt = 0; mt < 4; ++mt)
      evq[mt] = *(const f16x2*)(ehh + er80[mt] + kg0 + ch * 2);
    __syncthreads();                       // w2s[ch&1] staged
    if (ch + 1 < 10)
      stage_bytes(W2f + (kg0 + (ch + 1) * 2) * 7680, w2s[(ch + 1) & 1], 30720, tid);
    const f16* wb = w2s[ch & 1];
    #pragma unroll
    for (int i = 0; i < 2; ++i) {
      f16x8 af[4][3];
      #pragma unroll
      for (int mt = 0; mt < 4; ++mt) {
        f16 ev = evq[mt][i];
        f16x8 evv = {ev, ev, ev, ev, ev, ev, ev, ev};
        #pragma unroll
        for (int ks = 0; ks < 3; ++ks) af[mt][ks] = hsv[mt][ks] * evv;
      }
      const f16* wbi = wb + i * 7680;
      #pragma unroll
      for (int nt = 0; nt < 5; ++nt) {
        #pragma unroll
        for (int ks = 0; ks < 3; ++ks) {
          f16x8 bf = *(const f16x8*)(wbi + (nt * 3 + ks) * 512 + lane * 8);  // base+lane*16: conflict-free
          #pragma unroll
          for (int mt = 0; mt < 4; ++mt)
            acc[mt][nt] = __builtin_amdgcn_mfma_f32_16x16x32_f16(af[mt][ks], bf, acc[mt][nt], 0, 0, 0);
        }
      }
    }
  }
  // epilogue: C layout col=lane&15, row=(lane>>4)*4+reg; f16 stores to disjoint quarter-row
  #pragma unroll
  for (int mt = 0; mt < 4; ++mt) {
    #pragma unroll
    for (int reg = 0; reg < 4; ++reg) {
      int er = e0 + wave * 64 + mt * 16 + q * 4 + reg;
      f16* mp = m + (size_t)er * 320 + ksp * 80;
      #pragma unroll
      for (int nt = 0; nt < 5; ++nt)
        mp[nt * 16 + mr] = (f16)acc[mt][nt][reg];
    }
  }
}

// ---------------- gather: agg[n,i] = sum over incoming edges of all 4 K-quarters (f16 in, fp32 acc) ----
__global__ void gather_kernel(const f16* __restrict__ m, const int* __restrict__ count,
                              const int* __restrict__ bucket, f16* __restrict__ aggf) {
  int t = blockIdx.x * 384 + threadIdx.x;  // exactly 8192*96
  int n = t / 96, i = t - n * 96;
  float s = 0.f;
  if (i < 80) {
    int cnt = count[n]; if (cnt > 64) cnt = 64;
    const int* bk = bucket + n * 64;
    for (int j = 0; j < cnt; ++j) {
      const f16* mp = m + (size_t)bk[j] * 320;
      s += ((float)mp[i] + (float)mp[80 + i]) + ((float)mp[160 + i] + (float)mp[240 + i]);
    }
  }
  aggf[t] = (f16)s;
}

// ---------------- GRU gates GEMMs: G[0]=agg@WihT, G[1]=h@WhhT (G stored f16) ----------------
__global__ __launch_bounds__(256, 1) void grugemm_kernel(
    const f16* __restrict__ aggf, const f16* __restrict__ hf,
    const f16* __restrict__ WihT, const f16* __restrict__ WhhT,
    f16* __restrict__ G) {
  __shared__ __align__(16) f16 As[128 * 96];
  __shared__ __align__(16) f16 Bs[224 * 96];
  const int tid = threadIdx.x;
  const int bz = blockIdx.x >> 6, bm = blockIdx.x & 63;
  const int m0 = bm * 128;
  const f16* A = bz ? hf : aggf;
  const f16* B = bz ? WhhT : WihT;
  f16* out = G + bz * (NN * 224);
  stage_bytes(A + m0 * 96, As, 128 * 96 * 2, tid);
  stage_bytes(B, Bs, 224 * 96 * 2, tid);
  const int wave = tid >> 6, lane = tid & 63, q = lane >> 4, mr = lane & 15;
  __syncthreads();
  f16x8 af[2][3];
  #pragma unroll
  for (int mt = 0; mt < 2; ++mt)
    #pragma unroll
    for (int ks = 0; ks < 3; ++ks)
      af[mt][ks] = *(const f16x8*)(As + (wave * 32 + mt * 16 + mr) * 96 + ks * 32 + q * 8);
  f32x4 zero = {0.f, 0.f, 0.f, 0.f};
  f32x4 acc[2][14];
  #pragma unroll
  for (int mt = 0; mt < 2; ++mt)
    #pragma unroll
    for (int nt = 0; nt < 14; ++nt) acc[mt][nt] = zero;
  #pragma unroll
  for (int nt = 0; nt < 14; ++nt) {
    #pragma unroll
    for (int ks = 0; ks < 3; ++ks) {
      f16x8 bf = *(const f16x8*)(Bs + (nt * 16 + mr) * 96 + ks * 32 + q * 8);
      #pragma unroll
      for (int mt = 0; mt < 2; ++mt)
        acc[mt][nt] = __builtin_amdgcn_mfma_f32_16x16x32_f16(af[mt][ks], bf, acc[mt][nt], 0, 0, 0);
    }
  }
  #pragma unroll
  for (int mt = 0; mt < 2; ++mt)
    #pragma unroll
    for (int reg = 0; reg < 4; ++reg) {
      int row = m0 + wave * 32 + mt * 16 + q * 4 + reg;
      #pragma unroll
      for (int nt = 0; nt < 14; ++nt)
        out[row * 224 + nt * 16 + mr] = (f16)acc[mt][nt][reg];
    }
}

// ---------------- GRU elementwise update (G in f16) ----------------
__global__ void gate_kernel(const f16* __restrict__ G, const float* __restrict__ bih,
                            const float* __restrict__ bhh, float* __restrict__ h,
                            f16* __restrict__ hf) {
  int idx = blockIdx.x * 256 + threadIdx.x;  // exactly 8192*73
  int n = idx / 73, i = idx - n * 73;
  const f16* g0 = G + n * 224;
  const f16* g1 = G + NN * 224 + n * 224;
  float rr = (float)g0[i] + bih[i] + (float)g1[i] + bhh[i];
  rr = 1.f / (1.f + __expf(-rr));
  float zz = (float)g0[73 + i] + bih[73 + i] + (float)g1[73 + i] + bhh[73 + i];
  zz = 1.f / (1.f + __expf(-zz));
  float nx = (float)g0[146 + i] + bih[146 + i] + rr * ((float)g1[146 + i] + bhh[146 + i]);
  float nn_ = 2.f / (1.f + __expf(-2.f * nx)) - 1.f;
  float hv = h[n * 96 + i];
  float hn = (1.f - zz) * nn_ + zz * hv;
  h[n * 96 + i] = hn;
  hf[n * 96 + i] = (f16)hn;
}

// ---------------- Set2Set helpers ----------------
__device__ __forceinline__ float wred_sum(float v) {
  #pragma unroll
  for (int off = 32; off; off >>= 1) v += __shfl_xor(v, off, 64);
  return v;
}
// fp32-accumulating f16 dots (v_dot2_f32_f16)
__device__ __forceinline__ float dot8(f16x8 w, f16x8 x, float acc) {
#if HAS_FDOT2
  acc = __builtin_amdgcn_fdot2((f16x2)__builtin_shufflevector(w, w, 0, 1),
                               (f16x2)__builtin_shufflevector(x, x, 0, 1), acc, false);
  acc = __builtin_amdgcn_fdot2((f16x2)__builtin_shufflevector(w, w, 2, 3),
                               (f16x2)__builtin_shufflevector(x, x, 2, 3), acc, false);
  acc = __builtin_amdgcn_fdot2((f16x2)__builtin_shufflevector(w, w, 4, 5),
                               (f16x2)__builtin_shufflevector(x, x, 4, 5), acc, false);
  acc = __builtin_amdgcn_fdot2((f16x2)__builtin_shufflevector(w, w, 6, 7),
                               (f16x2)__builtin_shufflevector(x, x, 6, 7), acc, false);
#else
  #pragma unroll
  for (int e = 0; e < 8; ++e) acc += (float)w[e] * (float)x[e];
#endif
  return acc;
}
__device__ __forceinline__ float dot4(f16x4 w, f16x4 x, float acc) {
#if HAS_FDOT2
  acc = __builtin_amdgcn_fdot2((f16x2)__builtin_shufflevector(w, w, 0, 1),
                               (f16x2)__builtin_shufflevector(x, x, 0, 1), acc, false);
  acc = __builtin_amdgcn_fdot2((f16x2)__builtin_shufflevector(w, w, 2, 3),
                               (f16x2)__builtin_shufflevector(x, x, 2, 3), acc, false);
#else
  #pragma unroll
  for (int e = 0; e < 4; ++e) acc += (float)w[e] * (float)x[e];
#endif
  return acc;
}

#define S2SCAP 256   // absolute per-segment cap (binomial mean 128, sd 11)
#define NCAP 190     // rows cached in LDS; [NCAP,segT) via global fallback (normally empty)

// ---------------- Set2Set v7: (512,2) -> 256-VGPR budget so LSTM weights STAY resident ----
__global__ __launch_bounds__(512, 2) void s2s_kernel(
    const float* __restrict__ h, const f16* __restrict__ hf,
    const f16* __restrict__ Wcat,
    const float* __restrict__ lbih, const float* __restrict__ lbhh,
    const float* __restrict__ Wout, const float* __restrict__ bout,
    const int* __restrict__ segstarts, float* __restrict__ out) {
  __shared__ __align__(16) f16 hseg[NCAP * 84];   // 31920 B, row stride 84 f16 (b64-aligned)
  __shared__ __align__(16) f16 xcat[240];
  __shared__ float hhv[80];
  __shared__ float gatesv[292];
  __shared__ float earr[S2SCAP];
  __shared__ float red[4];
  __shared__ __align__(16) float rpart[19 * 80];
  const int t = threadIdx.x, b = blockIdx.x;
  const int wid = t >> 6, lane = t & 63;

  const int s0 = segstarts[b];
  int segT = segstarts[b + 1] - s0;
  if (segT > S2SCAP) segT = S2SCAP;
  const int c = segT < NCAP ? segT : NCAP;

  if (t < 240) xcat[t] = (f16)0.f;
  if (t < 80) hhv[t] = 0.f;

  // stage hseg rows (f16, cols 0..75 data incl. zero pads 73..75; cols 76..83 zeroed)
  for (int r = wid; r < c; r += 8) {
    if (lane < 19) {
      f16x4 v = *(const f16x4*)(hf + (size_t)(s0 + r) * 96 + lane * 4);
      *(f16x4*)(hseg + r * 84 + lane * 4) = v;
    } else if (lane < 21) {
      f16x4 z = {(f16)0.f, (f16)0.f, (f16)0.f, (f16)0.f};
      *(f16x4*)(hseg + r * 84 + 76 + (lane - 19) * 4) = z;
    }
  }

  const bool isg = (t >= 220);
  const int g2 = t - 220;
  float bias = 0.f;
  if (isg) bias = lbih[g2] + lbhh[g2];
  // LSTM weight row RESIDENT in registers (116 VGPR), loaded unconditionally (clamped row).
  f16x8 wihF[19], whhF[10];
  {
    const f16* wr = Wcat + (size_t)(isg ? g2 : 0) * 232;
    #pragma unroll
    for (int v = 0; v < 19; ++v) wihF[v] = *(const f16x8*)(wr + v * 8);
    #pragma unroll
    for (int v = 0; v < 10; ++v) whhF[v] = *(const f16x8*)(wr + 152 + v * 8);
  }
  const int nc = t / 10, fo = t - nc * 10;    // readout mapping (t<190)
  float creg = 0.f;                            // LSTM cell state (t<73)
  __syncthreads();

  for (int iter = 0; iter < 12; ++iter) {
    // ---- P1: LSTM gate matvec (292 threads), weights in regs, 4 accumulators ----
    if (isg) {
      float a0 = bias, a1 = 0.f, a2 = 0.f, a3 = 0.f;
      #pragma unroll
      for (int v = 0; v < 19; ++v) {
        f16x8 x = *(const f16x8*)(xcat + v * 8);
        int sel = v & 3;
        if (sel == 0) a0 = dot8(wihF[v], x, a0);
        else if (sel == 1) a1 = dot8(wihF[v], x, a1);
        else if (sel == 2) a2 = dot8(wihF[v], x, a2);
        else a3 = dot8(wihF[v], x, a3);
      }
      #pragma unroll
      for (int v = 0; v < 10; ++v) {
        f16x8 x = *(const f16x8*)(xcat + 152 + v * 8);
        int sel = v & 3;
        if (sel == 0) a0 = dot8(whhF[v], x, a0);
        else if (sel == 1) a1 = dot8(whhF[v], x, a1);
        else if (sel == 2) a2 = dot8(whhF[v], x, a2);
        else a3 = dot8(whhF[v], x, a3);
      }
      gatesv[g2] = (a0 + a1) + (a2 + a3);
    }
    __syncthreads();
    // ---- P2: LSTM elementwise update (t<73) ----
    if (t < 73) {
      float ig = 1.f / (1.f + __expf(-gatesv[t]));
      float fg = 1.f / (1.f + __expf(-gatesv[73 + t]));
      float gx = gatesv[146 + t];
      float gg = 2.f / (1.f + __expf(-2.f * gx)) - 1.f;
      float og = 1.f / (1.f + __expf(-gatesv[219 + t]));
      creg = fg * creg + ig * gg;
      float cth = 2.f / (1.f + __expf(-2.f * creg)) - 1.f;
      float hh = og * cth;
      hhv[t] = hh;
      xcat[t] = (f16)hh;        // q slot
      xcat[152 + t] = (f16)hh;  // hh slot
    }
    __syncthreads();
    // ---- P3: logits + exp + per-wave sums (t<192, node per thread, f16 dot) ----
    if (wid < 3) {
      float a = 0.f;
      if (t < c) {
        const f16* hp = hseg + t * 84;
        float e0 = 0.f, e1 = 0.f;
        #pragma unroll
        for (int k = 0; k < 9; ++k) {
          f16x4 h0 = *(const f16x4*)(hp + 8 * k);
          f16x4 h1 = *(const f16x4*)(hp + 8 * k + 4);
          f16x4 x0 = *(const f16x4*)(xcat + 8 * k);
          f16x4 x1 = *(const f16x4*)(xcat + 8 * k + 4);
          e0 = dot4(h0, x0, e0);
          e1 = dot4(h1, x1, e1);
        }
        f16x4 ht = *(const f16x4*)(hp + 72);
        f16x4 xt = *(const f16x4*)(xcat + 72);
        e0 = dot4(ht, xt, e0);
        a = __expf(fminf(e0 + e1, 80.f));  // logits bounded; no max-sub in fp32
        earr[t] = a;
      }
      float ws = wred_sum(a);
      if (lane == 0) red[wid] = ws;
    }
    // fallback logits for nodes >= NCAP (normally zero-trip)
    if (wid == 0) {
      float fa = 0.f;
      int n = NCAP + lane;
      if (n < segT) {
        const float* hr = h + (size_t)(s0 + n) * 96;
        float e = 0.f;
        for (int i = 0; i < 73; ++i) e += hr[i] * hhv[i];
        fa = __expf(fminf(e, 80.f));
        earr[n] = fa;
      }
      float ws2 = wred_sum(fa);
      if (lane == 0) red[3] = ws2;
    }
    __syncthreads();
    // ---- P4: weighted readout partials (t<190: chunk nc of 10 nodes, feature-octet fo) ----
    if (t < 190) {
      float r0 = 0.f, r1 = 0.f, r2 = 0.f, r3 = 0.f, r4 = 0.f, r5 = 0.f, r6 = 0.f, r7 = 0.f;
      #pragma unroll
      for (int j = 0; j < 10; ++j) {
        int n = nc * 10 + j;
        if (n < c) {
          float a = earr[n];
          const f16* hp = hseg + n * 84 + fo * 8;
          f16x4 v0 = *(const f16x4*)(hp);
          f16x4 v1 = *(const f16x4*)(hp + 4);
          r0 += a * (float)v0[0]; r1 += a * (float)v0[1];
          r2 += a * (float)v0[2]; r3 += a * (float)v0[3];
          r4 += a * (float)v1[0]; r5 += a * (float)v1[1];
          r6 += a * (float)v1[2]; r7 += a * (float)v1[3];
        }
      }
      if (nc == 18) {  // fallback nodes from global hf (normally zero-trip)
        for (int n = NCAP; n < segT; ++n) {
          float a = earr[n];
          const f16* hp = hf + (size_t)(s0 + n) * 96 + fo * 8;
          f16x4 v0 = *(const f16x4*)(hp);
          f16x4 v1 = *(const f16x4*)(hp + 4);
          r0 += a * (float)v0[0]; r1 += a * (float)v0[1];
          r2 += a * (float)v0[2]; r3 += a * (float)v0[3];
          r4 += a * (float)v1[0]; r5 += a * (float)v1[1];
          r6 += a * (float)v1[2]; r7 += a * (float)v1[3];
        }
      }
      f32x4 wa = {r0, r1, r2, r3}, wb = {r4, r5, r6, r7};
      *(f32x4*)(rpart + nc * 80 + fo * 8) = wa;
      *(f32x4*)(rpart + nc * 80 + fo * 8 + 4) = wb;
    }
    __syncthreads();
    // ---- P5: combine partials -> r into xcat (t<80) ----
    if (t < 80) {
      float S = red[0] + red[1] + red[2] + red[3];
      float invS = (S > 0.f) ? (1.f / S) : 0.f;
      float r = 0.f;
      #pragma unroll
      for (int ch = 0; ch < 19; ++ch) r += rpart[ch * 80 + t];
      if (t < 73) xcat[76 + t] = (f16)(r * invS);
    }
    __syncthreads();
  }
  // ---- output: out[b] = bout + hh . Wout ----
  if (t < 80) gatesv[t] = (t < 73) ? hhv[t] * Wout[t] : 0.f;
  __syncthreads();
  if (t == 0) {
    float a = bout[0];
    for (int i = 0; i < 73; ++i) a += gatesv[i];
    out[b] = a;
  }
}

// ---------------- workspace layout (bytes; ws_size = 256 MiB per harness fill) ----------------
#define OFF_H      0u          // float [8192][96]
#define OFF_G      3145728u    // f16 [2][8192][224] gate pre-activations
#define OFF_HF     17825792u   // f16 [8192][96]
#define OFF_AGGF   19398656u   // f16 [8192][96]
#define OFF_EHH    20971520u   // f16 [32768][80]
#define OFF_W2F    26214400u   // f16 [80][7680] fragment order
#define OFF_WIHT   27443200u   // f16 [224][96]
#define OFF_WHHT   27486208u   // f16 [224][96]
#define OFF_WCAT   27529216u   // f16 [292][232]
#define OFF_SEG    27664704u   // int [65]
#define OFF_CNT    27665024u   // int [8192]
#define OFF_BKT    27697792u   // int [8192][64]
#define OFF_M      29794944u   // f16 [32768][320] K-quarter partials (end ~50.8 MB)

extern "C" void kernel_launch(void* const* d_in, const int* in_sizes, int n_in,
                              void* d_out, int out_size, void* d_ws, size_t ws_size,
                              hipStream_t stream) {
  const float* nf   = (const float*)d_in[0];
  const float* ef   = (const float*)d_in[1];
  const float* W_in = (const float*)d_in[2];
  const float* b_in = (const float*)d_in[3];
  const float* W1   = (const float*)d_in[4];
  const float* b1   = (const float*)d_in[5];
  const float* W2   = (const float*)d_in[6];
  const float* b2   = (const float*)d_in[7];
  const float* gWih = (const float*)d_in[8];
  const float* gWhh = (const float*)d_in[9];
  const float* gbih = (const float*)d_in[10];
  const float* gbhh = (const float*)d_in[11];
  const float* lWih = (const float*)d_in[12];
  const float* lWhh = (const float*)d_in[13];
  const float* lbih = (const float*)d_in[14];
  const float* lbhh = (const float*)d_in[15];
  const float* Wout = (const float*)d_in[16];
  const float* bout = (const float*)d_in[17];
  const int* Esrc   = (const int*)d_in[18];
  const int* Etgt   = (const int*)d_in[19];
  const int* batch  = (const int*)d_in[20];

  char* ws = (char*)d_ws;
  float* h    = (float*)(ws + OFF_H);
  f16* G      = (f16*)(ws + OFF_G);
  f16* m      = (f16*)(ws + OFF_M);
  f16* hf     = (f16*)(ws + OFF_HF);
  f16* aggf   = (f16*)(ws + OFF_AGGF);
  f16* ehh    = (f16*)(ws + OFF_EHH);
  f16* W2f    = (f16*)(ws + OFF_W2F);
  f16* WihT   = (f16*)(ws + OFF_WIHT);
  f16* WhhT   = (f16*)(ws + OFF_WHHT);
  f16* Wcat   = (f16*)(ws + OFF_WCAT);
  int* segst  = (int*)(ws + OFF_SEG);
  int* cnt    = (int*)(ws + OFF_CNT);
  int* bkt    = (int*)(ws + OFF_BKT);

  hipMemsetAsync(cnt, 0, NN * sizeof(int), stream);
  prep_kernel<<<16273, 256, 0, stream>>>(nf, ef, W_in, b_in, W1, b1, W2, b2,
                                         gWih, gWhh, lWih, lWhh, batch, Etgt,
                                         h, hf, ehh, W2f, WihT, WhhT, Wcat,
                                         segst, cnt, bkt);
  for (int step = 0; step < 3; ++step) {
    vgemm_kernel<<<512, 256, 0, stream>>>(ehh, hf, W2f, Esrc, m);
    gather_kernel<<<2048, 384, 0, stream>>>(m, cnt, bkt, aggf);
    grugemm_kernel<<<128, 256, 0, stream>>>(aggf, hf, WihT, WhhT, G);
    gate_kernel<<<2336, 256, 0, stream>>>(G, gbih, gbhh, h, hf);
  }
  s2s_kernel<<<64, 512, 0, stream>>>(h, hf, Wcat, lbih, lbhh, Wout, bout, segst,
                                     (float*)d_out);
}